// Round 2
// baseline (280.868 us; speedup 1.0000x reference)
//
#include <hip/hip_runtime.h>
#include <hip/hip_bf16.h>
#include <stdint.h>

#define DM   1024
#define DKV  64
#define HEADS 16
#define BATCH 2
#define SEQ  2048
#define BS   (BATCH*SEQ)    // 4096
#define BHD  (BATCH*HEADS)  // 32

typedef __attribute__((ext_vector_type(8))) short bf16x8;
typedef __attribute__((ext_vector_type(4))) short bf16x4;
typedef __attribute__((ext_vector_type(4))) float f32x4;

// ---------- helpers ----------
__device__ inline unsigned short bf16_rtn(float f) {
  union { float f; unsigned u; } v; v.f = f;
  unsigned u = v.u;
  unsigned r = u + 0x7fffu + ((u >> 16) & 1u);
  return (unsigned short)(r >> 16);
}
__device__ inline float bf16_to_f(unsigned short h) {
  union { unsigned u; float f; } v; v.u = ((unsigned)h) << 16; return v.f;
}
// split x ≈ hi + lo, |lo| <= 2^-9 |x|, residual ~2^-18
__device__ inline void split_bf16(float x, unsigned short& hi, unsigned short& lo) {
  hi = bf16_rtn(x);
  lo = bf16_rtn(x - bf16_to_f(hi));
}

__device__ inline float fast_exp2(float x) {
#if __has_builtin(__builtin_amdgcn_exp2f)
  return __builtin_amdgcn_exp2f(x);
#else
  return exp2f(x);
#endif
}

__device__ inline f32x4 mfma16x16x16_bf16(bf16x4 a, bf16x4 b, f32x4 c) {
#if __has_builtin(__builtin_amdgcn_mfma_f32_16x16x16bf16_1k)
  return __builtin_amdgcn_mfma_f32_16x16x16bf16_1k(a, b, c, 0, 0, 0);
#else
  asm volatile("v_mfma_f32_16x16x16_bf16 %0, %1, %2, %0" : "+v"(c) : "v"(a), "v"(b));
  return c;
#endif
}

// stage 16B/lane: async direct-to-LDS (dest = wave-uniform base + lane*16)
__device__ inline void stage16(const unsigned short* g, unsigned short* lds_base, int lane) {
#if __has_builtin(__builtin_amdgcn_global_load_lds)
  __builtin_amdgcn_global_load_lds((__attribute__((address_space(1))) void*)(g),
                                   (__attribute__((address_space(3))) void*)(lds_base),
                                   16, 0, 0);
#else
  *(bf16x8*)(lds_base + lane * 8) = *(const bf16x8*)g;
#endif
}

// ---------- pack kernels ----------
// x -> split bf16 (hi, lo)
__global__ void cvt_x_split(const float* __restrict__ x,
                            unsigned short* __restrict__ xh, unsigned short* __restrict__ xl) {
  int i = (blockIdx.x * 256 + threadIdx.x) * 8;
  bf16x8 oh, ol;
  #pragma unroll
  for (int j = 0; j < 8; ++j) {
    unsigned short hi, lo;
    split_bf16(x[i + j], hi, lo);
    oh[j] = (short)hi; ol[j] = (short)lo;
  }
  *(bf16x8*)(xh + i) = oh;
  *(bf16x8*)(xl + i) = ol;
}

// WcatT[c'][m] split, c' = p*1024 + h*64 + k  (p: 0=Q,1=K,2=V), from W_p[h][m][k]
__global__ void pack_qkv_split(const float* __restrict__ Wq, const float* __restrict__ Wk,
                               const float* __restrict__ Wv,
                               unsigned short* __restrict__ Wh, unsigned short* __restrict__ Wl) {
  __shared__ float tile[64][65];
  int bid = blockIdx.x;               // p*256 + h*16 + mt
  int p = bid >> 8, h = (bid >> 4) & 15, mt = bid & 15;
  const float* W = (p == 0) ? Wq : (p == 1) ? Wk : Wv;
  const float* src = W + (size_t)h * (DM * DKV);
  int t = threadIdx.x;
  int m0 = mt * 64;
  #pragma unroll
  for (int pass = 0; pass < 16; ++pass) {
    int row = pass * 4 + (t >> 6), col = t & 63;
    tile[row][col] = src[(size_t)(m0 + row) * DKV + col];
  }
  __syncthreads();
  int cbase = p * 1024 + h * 64;
  #pragma unroll
  for (int pass = 0; pass < 16; ++pass) {
    int krow = pass * 4 + (t >> 6), mcol = t & 63;
    unsigned short hi, lo;
    split_bf16(tile[mcol][krow], hi, lo);
    size_t idx = (size_t)(cbase + krow) * DM + m0 + mcol;
    Wh[idx] = hi; Wl[idx] = lo;
  }
}

// WoT[mo][c] = Wo[c][mo], single bf16
__global__ void pack_wo(const float* __restrict__ Wo, unsigned short* __restrict__ WoT) {
  __shared__ float tile[64][65];
  int ib = blockIdx.x >> 4, jb = blockIdx.x & 15;
  int t = threadIdx.x;
  #pragma unroll
  for (int pass = 0; pass < 16; ++pass) {
    int row = pass * 4 + (t >> 6), col = t & 63;
    tile[row][col] = Wo[(size_t)(ib * 64 + row) * DM + jb * 64 + col];
  }
  __syncthreads();
  #pragma unroll
  for (int pass = 0; pass < 16; ++pass) {
    int a = pass * 4 + (t >> 6), b = t & 63;
    WoT[(size_t)(jb * 64 + a) * DM + ib * 64 + b] = bf16_rtn(tile[b][a]);
  }
}

// ---------- GEMM1: split-precision A@Bt^T, K=1024, tile 128x128x32 ----------
// acc = Ah*Bh + Ah*Bl + Al*Bh  (rel err ~2^-17). Epilogue: Q,K split-stored; V transposed bf16.
__global__ __launch_bounds__(256, 2)
void gemm1_split(const unsigned short* __restrict__ Ah, const unsigned short* __restrict__ Al,
                 const unsigned short* __restrict__ Bh, const unsigned short* __restrict__ Bl,
                 unsigned short* __restrict__ Qh, unsigned short* __restrict__ Ql,
                 unsigned short* __restrict__ Kh, unsigned short* __restrict__ Kl,
                 unsigned short* __restrict__ Vt) {
  __shared__ unsigned short AsH[128 * 32], AsL[128 * 32];
  __shared__ unsigned short BsH[128 * 32], BsL[128 * 32];
  const int tid = threadIdx.x;
  const int w = tid >> 6, lane = tid & 63;
  const int quad = lane >> 4, l16 = lane & 15;
  const int wm = w >> 1, wn = w & 1;
  const int bm = blockIdx.x, bn = blockIdx.y;

  f32x4 acc[4][4];
  #pragma unroll
  for (int i = 0; i < 4; ++i)
    #pragma unroll
    for (int j = 0; j < 4; ++j) acc[i][j] = (f32x4){0.f, 0.f, 0.f, 0.f};

  const int r4 = lane >> 2, c4 = lane & 3;
  const size_t offA = (size_t)(bm * 128 + w * 32 + r4) * DM + c4 * 8;
  const size_t offB = (size_t)(bn * 128 + w * 32 + r4) * DM + c4 * 8;
  unsigned short* lAh0 = AsH + (w * 32) * 32;      unsigned short* lAh1 = AsH + (w * 32 + 16) * 32;
  unsigned short* lAl0 = AsL + (w * 32) * 32;      unsigned short* lAl1 = AsL + (w * 32 + 16) * 32;
  unsigned short* lBh0 = BsH + (w * 32) * 32;      unsigned short* lBh1 = BsH + (w * 32 + 16) * 32;
  unsigned short* lBl0 = BsL + (w * 32) * 32;      unsigned short* lBl1 = BsL + (w * 32 + 16) * 32;

  for (int kk = 0; kk < DM / 32; ++kk) {
    stage16(Ah + offA + kk * 32,           lAh0, lane);
    stage16(Ah + offA + kk * 32 + 16 * DM, lAh1, lane);
    stage16(Al + offA + kk * 32,           lAl0, lane);
    stage16(Al + offA + kk * 32 + 16 * DM, lAl1, lane);
    stage16(Bh + offB + kk * 32,           lBh0, lane);
    stage16(Bh + offB + kk * 32 + 16 * DM, lBh1, lane);
    stage16(Bl + offB + kk * 32,           lBl0, lane);
    stage16(Bl + offB + kk * 32 + 16 * DM, lBl1, lane);
    asm volatile("s_waitcnt vmcnt(0)" ::: "memory");
    __syncthreads();
    bf16x8 afh[4], afl[4], bfh[4], bfl[4];
    #pragma unroll
    for (int mt = 0; mt < 4; ++mt) {
      afh[mt] = *(const bf16x8*)(AsH + (wm * 64 + mt * 16 + l16) * 32 + quad * 8);
      afl[mt] = *(const bf16x8*)(AsL + (wm * 64 + mt * 16 + l16) * 32 + quad * 8);
    }
    #pragma unroll
    for (int nt = 0; nt < 4; ++nt) {
      bfh[nt] = *(const bf16x8*)(BsH + (wn * 64 + nt * 16 + l16) * 32 + quad * 8);
      bfl[nt] = *(const bf16x8*)(BsL + (wn * 64 + nt * 16 + l16) * 32 + quad * 8);
    }
    #pragma unroll
    for (int mt = 0; mt < 4; ++mt)
      #pragma unroll
      for (int nt = 0; nt < 4; ++nt) {
        acc[mt][nt] = __builtin_amdgcn_mfma_f32_16x16x32_bf16(afh[mt], bfh[nt], acc[mt][nt], 0, 0, 0);
        acc[mt][nt] = __builtin_amdgcn_mfma_f32_16x16x32_bf16(afh[mt], bfl[nt], acc[mt][nt], 0, 0, 0);
        acc[mt][nt] = __builtin_amdgcn_mfma_f32_16x16x32_bf16(afl[mt], bfh[nt], acc[mt][nt], 0, 0, 0);
      }
    __syncthreads();
  }

  const float SCL = 0.18033688011112042f;  // (1/sqrt(64)) * log2(e), folded into Q
  #pragma unroll
  for (int mt = 0; mt < 4; ++mt) {
    int m_g = bm * 128 + wm * 64 + mt * 16 + quad * 4;
    #pragma unroll
    for (int nt = 0; nt < 4; ++nt) {
      int n_g = bn * 128 + wn * 64 + nt * 16 + l16;
      int p = n_g >> 10, h = (n_g >> 6) & 15, k = n_g & 63;
      #pragma unroll
      for (int r = 0; r < 4; ++r) {
        int row = m_g + r;
        int b = row >> 11, s = row & 2047;
        int bh = b * HEADS + h;
        float v = acc[mt][nt][r];
        if (p == 0) {
          unsigned short hi, lo; split_bf16(v * SCL, hi, lo);
          size_t idx = ((size_t)(bh * SEQ + s)) * DKV + k;
          Qh[idx] = hi; Ql[idx] = lo;
        } else if (p == 1) {
          unsigned short hi, lo; split_bf16(v, hi, lo);
          size_t idx = ((size_t)(bh * SEQ + s)) * DKV + k;
          Kh[idx] = hi; Kl[idx] = lo;
        } else {
          Vt[((size_t)(bh * DKV + k)) * SEQ + s] = bf16_rtn(v);
        }
      }
    }
  }
}

// ---------- flash attention: S^T = K.Q^T, split-precision scores ----------
__global__ __launch_bounds__(256, 2)
void flash(const unsigned short* __restrict__ Qh, const unsigned short* __restrict__ Ql,
           const unsigned short* __restrict__ Kh, const unsigned short* __restrict__ Kl,
           const unsigned short* __restrict__ Vt, unsigned short* __restrict__ ctx) {
  __shared__ unsigned short KtH[64 * 72];  // [key][d]
  __shared__ unsigned short KtL[64 * 72];
  __shared__ unsigned short Vts[64 * 72];  // [v][key]
  const int tid = threadIdx.x;
  const int w = tid >> 6, lane = tid & 63, quad = lane >> 4, l16 = lane & 15;
  const int bh = blockIdx.y;
  const int q0 = blockIdx.x * 128;

  // Q B-frags (scaled by SCL already): [n=q][k=d], split hi/lo
  bf16x8 qfh[2][2], qfl[2][2];
  #pragma unroll
  for (int qt = 0; qt < 2; ++qt) {
    int qrow = q0 + w * 32 + qt * 16 + l16;
    size_t base = ((size_t)(bh * SEQ + qrow)) * DKV + quad * 8;
    qfh[qt][0] = *(const bf16x8*)(Qh + base);
    qfh[qt][1] = *(const bf16x8*)(Qh + base + 32);
    qfl[qt][0] = *(const bf16x8*)(Ql + base);
    qfl[qt][1] = *(const bf16x8*)(Ql + base + 32);
  }

  float m_run[2] = {-1e30f, -1e30f};
  float l_run[2] = {0.f, 0.f};
  f32x4 acc[2][4];
  #pragma unroll
  for (int qt = 0; qt < 2; ++qt)
    #pragma unroll
    for (int vt = 0; vt < 4; ++vt) acc[qt][vt] = (f32x4){0.f, 0.f, 0.f, 0.f};

  const int srow = tid >> 3, sc8 = tid & 7;

  for (int kt = 0; kt < SEQ / 64; ++kt) {
    int kt0 = kt * 64;
    #pragma unroll
    for (int pass = 0; pass < 2; ++pass) {
      int row = pass * 32 + srow;
      size_t kidx = ((size_t)(bh * SEQ + kt0 + row)) * DKV + sc8 * 8;
      *(bf16x8*)(KtH + row * 72 + sc8 * 8) = *(const bf16x8*)(Kh + kidx);
      *(bf16x8*)(KtL + row * 72 + sc8 * 8) = *(const bf16x8*)(Kl + kidx);
      *(bf16x8*)(Vts + row * 72 + sc8 * 8) =
          *(const bf16x8*)(Vt + ((size_t)(bh * DKV + row)) * SEQ + kt0 + sc8 * 8);
    }
    __syncthreads();

    // S^T[key][q] = (Kh+Kl).(Qh+Ql)^T ≈ Kh.Qh + Kh.Ql + Kl.Qh
    f32x4 st[4][2];
    #pragma unroll
    for (int mt = 0; mt < 4; ++mt) {
      const unsigned short* kb = KtH + (mt * 16 + l16) * 72 + quad * 8;
      bf16x8 kah0 = *(const bf16x8*)(kb);
      bf16x8 kah1 = *(const bf16x8*)(kb + 32);
      const unsigned short* kbl = KtL + (mt * 16 + l16) * 72 + quad * 8;
      bf16x8 kal0 = *(const bf16x8*)(kbl);
      bf16x8 kal1 = *(const bf16x8*)(kbl + 32);
      #pragma unroll
      for (int qt = 0; qt < 2; ++qt) {
        f32x4 c = (f32x4){0.f, 0.f, 0.f, 0.f};
        c = __builtin_amdgcn_mfma_f32_16x16x32_bf16(kah0, qfh[qt][0], c, 0, 0, 0);
        c = __builtin_amdgcn_mfma_f32_16x16x32_bf16(kah1, qfh[qt][1], c, 0, 0, 0);
        c = __builtin_amdgcn_mfma_f32_16x16x32_bf16(kah0, qfl[qt][0], c, 0, 0, 0);
        c = __builtin_amdgcn_mfma_f32_16x16x32_bf16(kah1, qfl[qt][1], c, 0, 0, 0);
        c = __builtin_amdgcn_mfma_f32_16x16x32_bf16(kal0, qfh[qt][0], c, 0, 0, 0);
        c = __builtin_amdgcn_mfma_f32_16x16x32_bf16(kal1, qfh[qt][1], c, 0, 0, 0);
        st[mt][qt] = c;
      }
    }

    // online softmax per q-column (lane&15)
    bf16x4 pb[2][4];
    #pragma unroll
    for (int qt = 0; qt < 2; ++qt) {
      float cm = -1e30f;
      #pragma unroll
      for (int mt = 0; mt < 4; ++mt)
        #pragma unroll
        for (int r = 0; r < 4; ++r) cm = fmaxf(cm, st[mt][qt][r]);
      cm = fmaxf(cm, __shfl_xor(cm, 16));
      cm = fmaxf(cm, __shfl_xor(cm, 32));
      float mn = fmaxf(m_run[qt], cm);
      float alpha = fast_exp2(m_run[qt] - mn);
      m_run[qt] = mn;
      float ssum = 0.f;
      #pragma unroll
      for (int mt = 0; mt < 4; ++mt) {
        bf16x4 pk;
        #pragma unroll
        for (int r = 0; r < 4; ++r) {
          float p = fast_exp2(st[mt][qt][r] - mn);
          ssum += p;
          pk[r] = (short)bf16_rtn(p);
        }
        pb[qt][mt] = pk;
      }
      ssum += __shfl_xor(ssum, 16);
      ssum += __shfl_xor(ssum, 32);
      l_run[qt] = l_run[qt] * alpha + ssum;
      #pragma unroll
      for (int vt = 0; vt < 4; ++vt) acc[qt][vt] = acc[qt][vt] * alpha;
    }

    // O^T[v][q] += Vt-tile[m=v][k=key] . P^T[k=key][n=q]  (K=16, B direct from regs)
    #pragma unroll
    for (int vt = 0; vt < 4; ++vt) {
      #pragma unroll
      for (int mt = 0; mt < 4; ++mt) {
        bf16x4 va = *(const bf16x4*)(Vts + (vt * 16 + l16) * 72 + mt * 16 + quad * 4);
        #pragma unroll
        for (int qt = 0; qt < 2; ++qt)
          acc[qt][vt] = mfma16x16x16_bf16(va, pb[qt][mt], acc[qt][vt]);
      }
    }
    __syncthreads();
  }

  // epilogue: ctx[bs][h*64 + v] bf16
  int h = bh & 15, b = bh >> 4;
  #pragma unroll
  for (int qt = 0; qt < 2; ++qt) {
    float inv = 1.0f / l_run[qt];
    int bs = b * SEQ + q0 + w * 32 + qt * 16 + l16;
    #pragma unroll
    for (int vt = 0; vt < 4; ++vt)
      #pragma unroll
      for (int r = 0; r < 4; ++r)
        ctx[(size_t)bs * DM + h * 64 + vt * 16 + quad * 4 + r] = bf16_rtn(acc[qt][vt][r] * inv);
  }
}

// ---------- GEMM2: ctx[4096][1024] @ WoT[1024][1024]^T -> fp32 out ----------
__global__ __launch_bounds__(256, 2)
void gemm_out(const unsigned short* __restrict__ A, const unsigned short* __restrict__ Bt,
              float* __restrict__ out) {
  __shared__ unsigned short As[128 * 32];
  __shared__ unsigned short Bs[128 * 32];
  const int tid = threadIdx.x;
  const int w = tid >> 6, lane = tid & 63;
  const int quad = lane >> 4, l16 = lane & 15;
  const int wm = w >> 1, wn = w & 1;
  const int bm = blockIdx.x, bn = blockIdx.y;

  f32x4 acc[4][4];
  #pragma unroll
  for (int i = 0; i < 4; ++i)
    #pragma unroll
    for (int j = 0; j < 4; ++j) acc[i][j] = (f32x4){0.f, 0.f, 0.f, 0.f};

  const int r4 = lane >> 2, c4 = lane & 3;
  const unsigned short* gA0 = A  + (size_t)(bm * 128 + w * 32 + r4) * DM + c4 * 8;
  const unsigned short* gB0 = Bt + (size_t)(bn * 128 + w * 32 + r4) * DM + c4 * 8;
  unsigned short* lA0 = As + (w * 32) * 32;
  unsigned short* lA1 = As + (w * 32 + 16) * 32;
  unsigned short* lB0 = Bs + (w * 32) * 32;
  unsigned short* lB1 = Bs + (w * 32 + 16) * 32;

  for (int kk = 0; kk < DM / 32; ++kk) {
    stage16(gA0 + kk * 32,           lA0, lane);
    stage16(gA0 + kk * 32 + 16 * DM, lA1, lane);
    stage16(gB0 + kk * 32,           lB0, lane);
    stage16(gB0 + kk * 32 + 16 * DM, lB1, lane);
    asm volatile("s_waitcnt vmcnt(0)" ::: "memory");
    __syncthreads();
    bf16x8 af[4], bfr[4];
    #pragma unroll
    for (int mt = 0; mt < 4; ++mt)
      af[mt] = *(const bf16x8*)(As + (wm * 64 + mt * 16 + l16) * 32 + quad * 8);
    #pragma unroll
    for (int nt = 0; nt < 4; ++nt)
      bfr[nt] = *(const bf16x8*)(Bs + (wn * 64 + nt * 16 + l16) * 32 + quad * 8);
    #pragma unroll
    for (int mt = 0; mt < 4; ++mt)
      #pragma unroll
      for (int nt = 0; nt < 4; ++nt)
        acc[mt][nt] = __builtin_amdgcn_mfma_f32_16x16x32_bf16(af[mt], bfr[nt], acc[mt][nt], 0, 0, 0);
    __syncthreads();
  }

  #pragma unroll
  for (int mt = 0; mt < 4; ++mt) {
    int m_g = bm * 128 + wm * 64 + mt * 16 + quad * 4;
    #pragma unroll
    for (int nt = 0; nt < 4; ++nt) {
      int n_g = bn * 128 + wn * 64 + nt * 16 + l16;
      #pragma unroll
      for (int r = 0; r < 4; ++r)
        out[(size_t)(m_g + r) * DM + n_g] = acc[mt][nt][r];
    }
  }
}

// ---------- launch ----------
extern "C" void kernel_launch(void* const* d_in, const int* in_sizes, int n_in,
                              void* d_out, int out_size, void* d_ws, size_t ws_size,
                              hipStream_t stream) {
  const float* x  = (const float*)d_in[0];
  const float* Wk = (const float*)d_in[1];
  const float* Wq = (const float*)d_in[2];
  const float* Wv = (const float*)d_in[3];
  const float* Wo = (const float*)d_in[4];
  float* out = (float*)d_out;

  unsigned short* xh  = (unsigned short*)d_ws;                  // [4096][1024]
  unsigned short* xl  = xh  + (size_t)BS * DM;
  unsigned short* Wh  = xl  + (size_t)BS * DM;                  // [3072][1024]
  unsigned short* Wl  = Wh  + (size_t)3 * DM * DM;
  unsigned short* WoT = Wl  + (size_t)3 * DM * DM;              // [1024][1024]
  unsigned short* Qh  = WoT + (size_t)DM * DM;                  // [32][2048][64]
  unsigned short* Ql  = Qh  + (size_t)BHD * SEQ * DKV;
  unsigned short* Kh  = Ql  + (size_t)BHD * SEQ * DKV;
  unsigned short* Kl  = Kh  + (size_t)BHD * SEQ * DKV;
  unsigned short* Vtb = Kl  + (size_t)BHD * SEQ * DKV;          // [32][64][2048]
  unsigned short* ctx = Vtb + (size_t)BHD * SEQ * DKV;          // [4096][1024]

  cvt_x_split<<<(BS * DM) / (256 * 8), 256, 0, stream>>>(x, xh, xl);
  pack_qkv_split<<<3 * 16 * 16, 256, 0, stream>>>(Wq, Wk, Wv, Wh, Wl);
  pack_wo<<<16 * 16, 256, 0, stream>>>(Wo, WoT);
  gemm1_split<<<dim3(BS / 128, 3072 / 128), 256, 0, stream>>>(xh, xl, Wh, Wl, Qh, Ql, Kh, Kl, Vtb);
  flash<<<dim3(SEQ / 128, BHD), 256, 0, stream>>>(Qh, Ql, Kh, Kl, Vtb, ctx);
  gemm_out<<<dim3(BS / 128, DM / 128), 256, 0, stream>>>(ctx, WoT, out);
}

// Round 3
// 270.810 us; speedup vs baseline: 1.0371x; 1.0371x over previous
//
#include <hip/hip_runtime.h>
#include <hip/hip_bf16.h>
#include <stdint.h>

#define DM   1024
#define DKV  64
#define HEADS 16
#define BATCH 2
#define SEQ  2048
#define BS   (BATCH*SEQ)    // 4096
#define BHD  (BATCH*HEADS)  // 32

typedef __attribute__((ext_vector_type(8))) short bf16x8;
typedef __attribute__((ext_vector_type(4))) short bf16x4;
typedef __attribute__((ext_vector_type(4))) float f32x4;

// ---------- helpers ----------
__device__ inline unsigned fb(float f) { union { float f; unsigned u; } v; v.f = f; return v.u; }

__device__ inline unsigned short bf16_rtn(float f) {
  unsigned u = fb(f);
  unsigned r = u + 0x7fffu + ((u >> 16) & 1u);
  return (unsigned short)(r >> 16);
}
__device__ inline float bf16_to_f(unsigned short h) {
  union { unsigned u; float f; } v; v.u = ((unsigned)h) << 16; return v.f;
}
// split x ≈ hi + lo, |lo| <= 2^-9 |x|, residual ~2^-18
__device__ inline void split_bf16(float x, unsigned short& hi, unsigned short& lo) {
  hi = bf16_rtn(x);
  lo = bf16_rtn(x - bf16_to_f(hi));
}
// pack two fp32 -> two bf16 (round-half-up) in one dword via v_perm_b32
__device__ inline unsigned pack2_bf16(float lo_elem, float hi_elem) {
  return __builtin_amdgcn_perm(fb(hi_elem) + 0x8000u, fb(lo_elem) + 0x8000u, 0x07060302u);
}

__device__ inline float fast_exp2(float x) {
#if __has_builtin(__builtin_amdgcn_exp2f)
  return __builtin_amdgcn_exp2f(x);
#else
  return exp2f(x);
#endif
}

__device__ inline f32x4 mfma16x16x16_bf16(bf16x4 a, bf16x4 b, f32x4 c) {
#if __has_builtin(__builtin_amdgcn_mfma_f32_16x16x16bf16_1k)
  return __builtin_amdgcn_mfma_f32_16x16x16bf16_1k(a, b, c, 0, 0, 0);
#else
  asm volatile("v_mfma_f32_16x16x16_bf16 %0, %1, %2, %0" : "+v"(c) : "v"(a), "v"(b));
  return c;
#endif
}

// stage 16B/lane: async direct-to-LDS (dest = wave-uniform base + lane*16)
__device__ inline void stage16(const unsigned short* g, unsigned short* lds_base, int lane) {
#if __has_builtin(__builtin_amdgcn_global_load_lds)
  __builtin_amdgcn_global_load_lds((__attribute__((address_space(1))) void*)(g),
                                   (__attribute__((address_space(3))) void*)(lds_base),
                                   16, 0, 0);
#else
  *(bf16x8*)(lds_base + lane * 8) = *(const bf16x8*)g;
#endif
}

// XOR-swizzled LDS index for a 64-col bf16 tile (8 chunks of 8 shorts per row)
__device__ inline int swz(int row, int chunk) {
  return row * 64 + (((chunk ^ (row & 7)) & 7) << 3);
}

// ---------- pack kernels ----------
__global__ void cvt_x_split(const float* __restrict__ x,
                            unsigned short* __restrict__ xh, unsigned short* __restrict__ xl) {
  int i = (blockIdx.x * 256 + threadIdx.x) * 8;
  bf16x8 oh, ol;
  #pragma unroll
  for (int j = 0; j < 8; ++j) {
    unsigned short hi, lo;
    split_bf16(x[i + j], hi, lo);
    oh[j] = (short)hi; ol[j] = (short)lo;
  }
  *(bf16x8*)(xh + i) = oh;
  *(bf16x8*)(xl + i) = ol;
}

// WcatT[c'][m] split, c' = p*1024 + h*64 + k  (p: 0=Q,1=K,2=V), from W_p[h][m][k]
__global__ void pack_qkv_split(const float* __restrict__ Wq, const float* __restrict__ Wk,
                               const float* __restrict__ Wv,
                               unsigned short* __restrict__ Wh, unsigned short* __restrict__ Wl) {
  __shared__ float tile[64][65];
  int bid = blockIdx.x;               // p*256 + h*16 + mt
  int p = bid >> 8, h = (bid >> 4) & 15, mt = bid & 15;
  const float* W = (p == 0) ? Wq : (p == 1) ? Wk : Wv;
  const float* src = W + (size_t)h * (DM * DKV);
  int t = threadIdx.x;
  int m0 = mt * 64;
  #pragma unroll
  for (int pass = 0; pass < 16; ++pass) {
    int row = pass * 4 + (t >> 6), col = t & 63;
    tile[row][col] = src[(size_t)(m0 + row) * DKV + col];
  }
  __syncthreads();
  int cbase = p * 1024 + h * 64;
  #pragma unroll
  for (int pass = 0; pass < 16; ++pass) {
    int krow = pass * 4 + (t >> 6), mcol = t & 63;
    unsigned short hi, lo;
    split_bf16(tile[mcol][krow], hi, lo);
    size_t idx = (size_t)(cbase + krow) * DM + m0 + mcol;
    Wh[idx] = hi; Wl[idx] = lo;
  }
}

// WoT[mo][c] = Wo[c][mo], single bf16
__global__ void pack_wo(const float* __restrict__ Wo, unsigned short* __restrict__ WoT) {
  __shared__ float tile[64][65];
  int ib = blockIdx.x >> 4, jb = blockIdx.x & 15;
  int t = threadIdx.x;
  #pragma unroll
  for (int pass = 0; pass < 16; ++pass) {
    int row = pass * 4 + (t >> 6), col = t & 63;
    tile[row][col] = Wo[(size_t)(ib * 64 + row) * DM + jb * 64 + col];
  }
  __syncthreads();
  #pragma unroll
  for (int pass = 0; pass < 16; ++pass) {
    int a = pass * 4 + (t >> 6), b = t & 63;
    WoT[(size_t)(jb * 64 + a) * DM + ib * 64 + b] = bf16_rtn(tile[b][a]);
  }
}

// ---------- gemm_qk: split-precision x@Wqk^T, N=2048, tile 128x128x32 ----------
// grid dim3(16=bn, 32=bm): id%8 = bn%8 -> weight tiles pinned per XCD
__global__ __launch_bounds__(256, 2)
void gemm_qk(const unsigned short* __restrict__ Ah, const unsigned short* __restrict__ Al,
             const unsigned short* __restrict__ Bh, const unsigned short* __restrict__ Bl,
             unsigned short* __restrict__ Qh, unsigned short* __restrict__ Ql,
             unsigned short* __restrict__ Kh, unsigned short* __restrict__ Kl) {
  __shared__ unsigned short AsH[128 * 32], AsL[128 * 32];
  __shared__ unsigned short BsH[128 * 32], BsL[128 * 32];
  const int tid = threadIdx.x;
  const int w = tid >> 6, lane = tid & 63;
  const int quad = lane >> 4, l16 = lane & 15;
  const int wm = w >> 1, wn = w & 1;
  const int bn = blockIdx.x, bm = blockIdx.y;

  f32x4 acc[4][4];
  #pragma unroll
  for (int i = 0; i < 4; ++i)
    #pragma unroll
    for (int j = 0; j < 4; ++j) acc[i][j] = (f32x4){0.f, 0.f, 0.f, 0.f};

  const int r4 = lane >> 2, c4 = lane & 3;
  const size_t offA = (size_t)(bm * 128 + w * 32 + r4) * DM + c4 * 8;
  const size_t offB = (size_t)(bn * 128 + w * 32 + r4) * DM + c4 * 8;
  unsigned short* lAh0 = AsH + (w * 32) * 32;      unsigned short* lAh1 = AsH + (w * 32 + 16) * 32;
  unsigned short* lAl0 = AsL + (w * 32) * 32;      unsigned short* lAl1 = AsL + (w * 32 + 16) * 32;
  unsigned short* lBh0 = BsH + (w * 32) * 32;      unsigned short* lBh1 = BsH + (w * 32 + 16) * 32;
  unsigned short* lBl0 = BsL + (w * 32) * 32;      unsigned short* lBl1 = BsL + (w * 32 + 16) * 32;

  for (int kk = 0; kk < DM / 32; ++kk) {
    stage16(Ah + offA + kk * 32,           lAh0, lane);
    stage16(Ah + offA + kk * 32 + 16 * DM, lAh1, lane);
    stage16(Al + offA + kk * 32,           lAl0, lane);
    stage16(Al + offA + kk * 32 + 16 * DM, lAl1, lane);
    stage16(Bh + offB + kk * 32,           lBh0, lane);
    stage16(Bh + offB + kk * 32 + 16 * DM, lBh1, lane);
    stage16(Bl + offB + kk * 32,           lBl0, lane);
    stage16(Bl + offB + kk * 32 + 16 * DM, lBl1, lane);
    asm volatile("s_waitcnt vmcnt(0)" ::: "memory");
    __syncthreads();
    bf16x8 afh[4], afl[4], bfh[4], bfl[4];
    #pragma unroll
    for (int mt = 0; mt < 4; ++mt) {
      afh[mt] = *(const bf16x8*)(AsH + (wm * 64 + mt * 16 + l16) * 32 + quad * 8);
      afl[mt] = *(const bf16x8*)(AsL + (wm * 64 + mt * 16 + l16) * 32 + quad * 8);
    }
    #pragma unroll
    for (int nt = 0; nt < 4; ++nt) {
      bfh[nt] = *(const bf16x8*)(BsH + (wn * 64 + nt * 16 + l16) * 32 + quad * 8);
      bfl[nt] = *(const bf16x8*)(BsL + (wn * 64 + nt * 16 + l16) * 32 + quad * 8);
    }
    #pragma unroll
    for (int mt = 0; mt < 4; ++mt)
      #pragma unroll
      for (int nt = 0; nt < 4; ++nt) {
        acc[mt][nt] = __builtin_amdgcn_mfma_f32_16x16x32_bf16(afh[mt], bfh[nt], acc[mt][nt], 0, 0, 0);
        acc[mt][nt] = __builtin_amdgcn_mfma_f32_16x16x32_bf16(afh[mt], bfl[nt], acc[mt][nt], 0, 0, 0);
        acc[mt][nt] = __builtin_amdgcn_mfma_f32_16x16x32_bf16(afl[mt], bfh[nt], acc[mt][nt], 0, 0, 0);
      }
    __syncthreads();
  }

  const float SCL = 0.18033688011112042f;  // (1/sqrt(64)) * log2(e), folded into Q
  #pragma unroll
  for (int mt = 0; mt < 4; ++mt) {
    int m_g = bm * 128 + wm * 64 + mt * 16 + quad * 4;
    #pragma unroll
    for (int nt = 0; nt < 4; ++nt) {
      int n_g = bn * 128 + wn * 64 + nt * 16 + l16;
      int p = n_g >> 10, h = (n_g >> 6) & 15, k = n_g & 63;
      #pragma unroll
      for (int r = 0; r < 4; ++r) {
        int row = m_g + r;
        int b = row >> 11, s = row & 2047;
        int bh = b * HEADS + h;
        float v = acc[mt][nt][r];
        size_t idx = ((size_t)(bh * SEQ + s)) * DKV + k;
        unsigned short hi, lo;
        if (p == 0) {
          split_bf16(v * SCL, hi, lo);
          Qh[idx] = hi; Ql[idx] = lo;
        } else {
          split_bf16(v, hi, lo);
          Kh[idx] = hi; Kl[idx] = lo;
        }
      }
    }
  }
}

// ---------- gemm_v: plain bf16 x@Wv^T -> Vt transposed. grid dim3(8=bn, 32=bm) ----------
__global__ __launch_bounds__(256, 2)
void gemm_v(const unsigned short* __restrict__ A, const unsigned short* __restrict__ Bt,
            unsigned short* __restrict__ Vt) {
  __shared__ unsigned short As[128 * 32];
  __shared__ unsigned short Bs[128 * 32];
  const int tid = threadIdx.x;
  const int w = tid >> 6, lane = tid & 63;
  const int quad = lane >> 4, l16 = lane & 15;
  const int wm = w >> 1, wn = w & 1;
  const int bn = blockIdx.x, bm = blockIdx.y;

  f32x4 acc[4][4];
  #pragma unroll
  for (int i = 0; i < 4; ++i)
    #pragma unroll
    for (int j = 0; j < 4; ++j) acc[i][j] = (f32x4){0.f, 0.f, 0.f, 0.f};

  const int r4 = lane >> 2, c4 = lane & 3;
  const unsigned short* gA0 = A  + (size_t)(bm * 128 + w * 32 + r4) * DM + c4 * 8;
  const unsigned short* gB0 = Bt + (size_t)(bn * 128 + w * 32 + r4) * DM + c4 * 8;
  unsigned short* lA0 = As + (w * 32) * 32;
  unsigned short* lA1 = As + (w * 32 + 16) * 32;
  unsigned short* lB0 = Bs + (w * 32) * 32;
  unsigned short* lB1 = Bs + (w * 32 + 16) * 32;

  for (int kk = 0; kk < DM / 32; ++kk) {
    stage16(gA0 + kk * 32,           lA0, lane);
    stage16(gA0 + kk * 32 + 16 * DM, lA1, lane);
    stage16(gB0 + kk * 32,           lB0, lane);
    stage16(gB0 + kk * 32 + 16 * DM, lB1, lane);
    asm volatile("s_waitcnt vmcnt(0)" ::: "memory");
    __syncthreads();
    bf16x8 af[4], bfr[4];
    #pragma unroll
    for (int mt = 0; mt < 4; ++mt)
      af[mt] = *(const bf16x8*)(As + (wm * 64 + mt * 16 + l16) * 32 + quad * 8);
    #pragma unroll
    for (int nt = 0; nt < 4; ++nt)
      bfr[nt] = *(const bf16x8*)(Bs + (wn * 64 + nt * 16 + l16) * 32 + quad * 8);
    #pragma unroll
    for (int mt = 0; mt < 4; ++mt)
      #pragma unroll
      for (int nt = 0; nt < 4; ++nt)
        acc[mt][nt] = __builtin_amdgcn_mfma_f32_16x16x32_bf16(af[mt], bfr[nt], acc[mt][nt], 0, 0, 0);
    __syncthreads();
  }

  #pragma unroll
  for (int mt = 0; mt < 4; ++mt) {
    int m_g = bm * 128 + wm * 64 + mt * 16 + quad * 4;
    #pragma unroll
    for (int nt = 0; nt < 4; ++nt) {
      int n_g = bn * 128 + wn * 64 + nt * 16 + l16;   // 0..1023 within V block
      int h = n_g >> 6, k = n_g & 63;
      #pragma unroll
      for (int r = 0; r < 4; ++r) {
        int row = m_g + r;
        int b = row >> 11, s = row & 2047;
        int bh = b * HEADS + h;
        Vt[((size_t)(bh * DKV + k)) * SEQ + s] = bf16_rtn(acc[mt][nt][r]);
      }
    }
  }
}

// ---------- flash: S^T = K.Q^T (split), P^T C-layout == K=16 B-layout ----------
// grid dim3(32=bh, 16=qb): id%8 = bh%8 -> each head's K/V pinned to one XCD L2.
__global__ __launch_bounds__(256, 2)
void flash(const unsigned short* __restrict__ Qh, const unsigned short* __restrict__ Ql,
           const unsigned short* __restrict__ Kh, const unsigned short* __restrict__ Kl,
           const unsigned short* __restrict__ Vt, unsigned short* __restrict__ ctx) {
  __shared__ unsigned short KtH[64 * 64], KtL[64 * 64], Vts[64 * 64];  // XOR-swizzled
  const int tid = threadIdx.x;
  const int w = tid >> 6, lane = tid & 63, quad = lane >> 4, l16 = lane & 15;
  const int bh = blockIdx.x;
  const int q0 = blockIdx.y * 128;

  // Q B-frags (scaled by SCL already): [n=q][k=d], split hi/lo
  bf16x8 qfh[2][2], qfl[2][2];
  #pragma unroll
  for (int qt = 0; qt < 2; ++qt) {
    int qrow = q0 + w * 32 + qt * 16 + l16;
    size_t base = ((size_t)(bh * SEQ + qrow)) * DKV + quad * 8;
    qfh[qt][0] = *(const bf16x8*)(Qh + base);
    qfh[qt][1] = *(const bf16x8*)(Qh + base + 32);
    qfl[qt][0] = *(const bf16x8*)(Ql + base);
    qfl[qt][1] = *(const bf16x8*)(Ql + base + 32);
  }

  float m_run[2] = {-1e30f, -1e30f};
  float l_run[2] = {0.f, 0.f};
  f32x4 acc[2][4];
  #pragma unroll
  for (int qt = 0; qt < 2; ++qt)
    #pragma unroll
    for (int vt = 0; vt < 4; ++vt) acc[qt][vt] = (f32x4){0.f, 0.f, 0.f, 0.f};

  const int srow = tid >> 3, sc8 = tid & 7;   // 32 rows/pass, 8 chunks/row

  // register-prefetch pipeline
  bf16x8 rkh[2], rkl[2], rv[2];
  #pragma unroll
  for (int p = 0; p < 2; ++p) {
    int row = p * 32 + srow;
    size_t kidx = ((size_t)(bh * SEQ + row)) * DKV + sc8 * 8;
    rkh[p] = *(const bf16x8*)(Kh + kidx);
    rkl[p] = *(const bf16x8*)(Kl + kidx);
    rv[p]  = *(const bf16x8*)(Vt + ((size_t)(bh * DKV + row)) * SEQ + sc8 * 8);
  }

  for (int kt = 0; kt < SEQ / 64; ++kt) {
    __syncthreads();
    #pragma unroll
    for (int p = 0; p < 2; ++p) {
      int row = p * 32 + srow;
      int o = swz(row, sc8);
      *(bf16x8*)(KtH + o) = rkh[p];
      *(bf16x8*)(KtL + o) = rkl[p];
      *(bf16x8*)(Vts + o) = rv[p];
    }
    __syncthreads();
    if (kt + 1 < SEQ / 64) {
      int kt0 = (kt + 1) * 64;
      #pragma unroll
      for (int p = 0; p < 2; ++p) {
        int row = p * 32 + srow;
        size_t kidx = ((size_t)(bh * SEQ + kt0 + row)) * DKV + sc8 * 8;
        rkh[p] = *(const bf16x8*)(Kh + kidx);
        rkl[p] = *(const bf16x8*)(Kl + kidx);
        rv[p]  = *(const bf16x8*)(Vt + ((size_t)(bh * DKV + row)) * SEQ + kt0 + sc8 * 8);
      }
    }

    // S^T[key][q] = Kh.Qh + Kh.Ql + Kl.Qh
    f32x4 st[4][2];
    #pragma unroll
    for (int mt = 0; mt < 4; ++mt) {
      int rowA = mt * 16 + l16;
      bf16x8 kah0 = *(const bf16x8*)(KtH + swz(rowA, quad));
      bf16x8 kah1 = *(const bf16x8*)(KtH + swz(rowA, quad + 4));
      bf16x8 kal0 = *(const bf16x8*)(KtL + swz(rowA, quad));
      bf16x8 kal1 = *(const bf16x8*)(KtL + swz(rowA, quad + 4));
      #pragma unroll
      for (int qt = 0; qt < 2; ++qt) {
        f32x4 c = (f32x4){0.f, 0.f, 0.f, 0.f};
        c = __builtin_amdgcn_mfma_f32_16x16x32_bf16(kah0, qfh[qt][0], c, 0, 0, 0);
        c = __builtin_amdgcn_mfma_f32_16x16x32_bf16(kah1, qfh[qt][1], c, 0, 0, 0);
        c = __builtin_amdgcn_mfma_f32_16x16x32_bf16(kah0, qfl[qt][0], c, 0, 0, 0);
        c = __builtin_amdgcn_mfma_f32_16x16x32_bf16(kah1, qfl[qt][1], c, 0, 0, 0);
        c = __builtin_amdgcn_mfma_f32_16x16x32_bf16(kal0, qfh[qt][0], c, 0, 0, 0);
        c = __builtin_amdgcn_mfma_f32_16x16x32_bf16(kal1, qfh[qt][1], c, 0, 0, 0);
        st[mt][qt] = c;
      }
    }

    // online softmax per q-column (lane&15); vote-skip rescale when max unchanged
    bf16x4 pb[2][4];
    #pragma unroll
    for (int qt = 0; qt < 2; ++qt) {
      float cm = -1e30f;
      #pragma unroll
      for (int mt = 0; mt < 4; ++mt)
        #pragma unroll
        for (int r = 0; r < 4; ++r) cm = fmaxf(cm, st[mt][qt][r]);
      cm = fmaxf(cm, __shfl_xor(cm, 16));
      cm = fmaxf(cm, __shfl_xor(cm, 32));
      bool upd = cm > m_run[qt];
      float mn = upd ? cm : m_run[qt];
      float ssum = 0.f;
      #pragma unroll
      for (int mt = 0; mt < 4; ++mt) {
        float p0 = fast_exp2(st[mt][qt][0] - mn);
        float p1 = fast_exp2(st[mt][qt][1] - mn);
        float p2 = fast_exp2(st[mt][qt][2] - mn);
        float p3 = fast_exp2(st[mt][qt][3] - mn);
        ssum += (p0 + p1) + (p2 + p3);
        union { bf16x4 v; unsigned u2[2]; } pk;
        pk.u2[0] = pack2_bf16(p0, p1);
        pk.u2[1] = pack2_bf16(p2, p3);
        pb[qt][mt] = pk.v;
      }
      ssum += __shfl_xor(ssum, 16);
      ssum += __shfl_xor(ssum, 32);
      if (__ballot(upd)) {
        float alpha = fast_exp2(m_run[qt] - mn);
        m_run[qt] = mn;
        l_run[qt] = l_run[qt] * alpha + ssum;
        #pragma unroll
        for (int vt = 0; vt < 4; ++vt) acc[qt][vt] = acc[qt][vt] * alpha;
      } else {
        l_run[qt] += ssum;
      }
    }

    // O^T[v][q] += Vt-tile[m=v][k=key] . P^T[k=key][n=q]  (K=16, B direct from regs)
    #pragma unroll
    for (int vt = 0; vt < 4; ++vt) {
      #pragma unroll
      for (int mt = 0; mt < 4; ++mt) {
        int row = vt * 16 + l16;
        int addr = row * 64 + ((((mt * 2 + (quad >> 1)) ^ (row & 7)) & 7) << 3) + (quad & 1) * 4;
        bf16x4 va = *(const bf16x4*)(Vts + addr);
        #pragma unroll
        for (int qt = 0; qt < 2; ++qt)
          acc[qt][vt] = mfma16x16x16_bf16(va, pb[qt][mt], acc[qt][vt]);
      }
    }
  }

  // epilogue: ctx[bs][h*64 + v] bf16 (perm-packed 8B stores)
  int h = bh & 15, b = bh >> 4;
  #pragma unroll
  for (int qt = 0; qt < 2; ++qt) {
    float inv = 1.0f / l_run[qt];
    int bs = b * SEQ + q0 + w * 32 + qt * 16 + l16;
    #pragma unroll
    for (int vt = 0; vt < 4; ++vt) {
      union { bf16x4 v; unsigned u2[2]; } pk;
      pk.u2[0] = pack2_bf16(acc[qt][vt][0] * inv, acc[qt][vt][1] * inv);
      pk.u2[1] = pack2_bf16(acc[qt][vt][2] * inv, acc[qt][vt][3] * inv);
      *(bf16x4*)(ctx + (size_t)bs * DM + h * 64 + vt * 16 + quad * 4) = pk.v;
    }
  }
}

// ---------- GEMM2: ctx @ WoT^T -> fp32 out. grid dim3(8=bn, 32=bm) ----------
__global__ __launch_bounds__(256, 2)
void gemm_out(const unsigned short* __restrict__ A, const unsigned short* __restrict__ Bt,
              float* __restrict__ out) {
  __shared__ unsigned short As[128 * 32];
  __shared__ unsigned short Bs[128 * 32];
  const int tid = threadIdx.x;
  const int w = tid >> 6, lane = tid & 63;
  const int quad = lane >> 4, l16 = lane & 15;
  const int wm = w >> 1, wn = w & 1;
  const int bn = blockIdx.x, bm = blockIdx.y;

  f32x4 acc[4][4];
  #pragma unroll
  for (int i = 0; i < 4; ++i)
    #pragma unroll
    for (int j = 0; j < 4; ++j) acc[i][j] = (f32x4){0.f, 0.f, 0.f, 0.f};

  const int r4 = lane >> 2, c4 = lane & 3;
  const unsigned short* gA0 = A  + (size_t)(bm * 128 + w * 32 + r4) * DM + c4 * 8;
  const unsigned short* gB0 = Bt + (size_t)(bn * 128 + w * 32 + r4) * DM + c4 * 8;
  unsigned short* lA0 = As + (w * 32) * 32;
  unsigned short* lA1 = As + (w * 32 + 16) * 32;
  unsigned short* lB0 = Bs + (w * 32) * 32;
  unsigned short* lB1 = Bs + (w * 32 + 16) * 32;

  for (int kk = 0; kk < DM / 32; ++kk) {
    stage16(gA0 + kk * 32,           lA0, lane);
    stage16(gA0 + kk * 32 + 16 * DM, lA1, lane);
    stage16(gB0 + kk * 32,           lB0, lane);
    stage16(gB0 + kk * 32 + 16 * DM, lB1, lane);
    asm volatile("s_waitcnt vmcnt(0)" ::: "memory");
    __syncthreads();
    bf16x8 af[4], bfr[4];
    #pragma unroll
    for (int mt = 0; mt < 4; ++mt)
      af[mt] = *(const bf16x8*)(As + (wm * 64 + mt * 16 + l16) * 32 + quad * 8);
    #pragma unroll
    for (int nt = 0; nt < 4; ++nt)
      bfr[nt] = *(const bf16x8*)(Bs + (wn * 64 + nt * 16 + l16) * 32 + quad * 8);
    #pragma unroll
    for (int mt = 0; mt < 4; ++mt)
      #pragma unroll
      for (int nt = 0; nt < 4; ++nt)
        acc[mt][nt] = __builtin_amdgcn_mfma_f32_16x16x32_bf16(af[mt], bfr[nt], acc[mt][nt], 0, 0, 0);
    __syncthreads();
  }

  #pragma unroll
  for (int mt = 0; mt < 4; ++mt) {
    int m_g = bm * 128 + wm * 64 + mt * 16 + quad * 4;
    #pragma unroll
    for (int nt = 0; nt < 4; ++nt) {
      int n_g = bn * 128 + wn * 64 + nt * 16 + l16;
      #pragma unroll
      for (int r = 0; r < 4; ++r)
        out[(size_t)(m_g + r) * DM + n_g] = acc[mt][nt][r];
    }
  }
}

// ---------- launch ----------
extern "C" void kernel_launch(void* const* d_in, const int* in_sizes, int n_in,
                              void* d_out, int out_size, void* d_ws, size_t ws_size,
                              hipStream_t stream) {
  const float* x  = (const float*)d_in[0];
  const float* Wk = (const float*)d_in[1];
  const float* Wq = (const float*)d_in[2];
  const float* Wv = (const float*)d_in[3];
  const float* Wo = (const float*)d_in[4];
  float* out = (float*)d_out;

  unsigned short* xh  = (unsigned short*)d_ws;                  // [4096][1024]
  unsigned short* xl  = xh  + (size_t)BS * DM;
  unsigned short* Wh  = xl  + (size_t)BS * DM;                  // [3072][1024]
  unsigned short* Wl  = Wh  + (size_t)3 * DM * DM;
  unsigned short* WoT = Wl  + (size_t)3 * DM * DM;              // [1024][1024]
  unsigned short* Qh  = WoT + (size_t)DM * DM;                  // [32][2048][64]
  unsigned short* Ql  = Qh  + (size_t)BHD * SEQ * DKV;
  unsigned short* Kh  = Ql  + (size_t)BHD * SEQ * DKV;
  unsigned short* Kl  = Kh  + (size_t)BHD * SEQ * DKV;
  unsigned short* Vtb = Kl  + (size_t)BHD * SEQ * DKV;          // [32][64][2048]
  unsigned short* ctx = Vtb + (size_t)BHD * SEQ * DKV;          // [4096][1024]

  cvt_x_split<<<(BS * DM) / (256 * 8), 256, 0, stream>>>(x, xh, xl);
  pack_qkv_split<<<3 * 16 * 16, 256, 0, stream>>>(Wq, Wk, Wv, Wh, Wl);
  pack_wo<<<16 * 16, 256, 0, stream>>>(Wo, WoT);
  gemm_qk<<<dim3(16, 32), 256, 0, stream>>>(xh, xl, Wh, Wl, Qh, Ql, Kh, Kl);
  gemm_v<<<dim3(8, 32), 256, 0, stream>>>(xh, Wh + (size_t)2048 * DM, Vtb);
  flash<<<dim3(BHD, SEQ / 128), 256, 0, stream>>>(Qh, Ql, Kh, Kl, Vtb, ctx);
  gemm_out<<<dim3(8, 32), 256, 0, stream>>>(ctx, WoT, out);
}